// Round 1
// 487.012 us; speedup vs baseline: 1.0177x; 1.0177x over previous
//
#include <hip/hip_runtime.h>

#define NC 21
#define NB 8
#define HW (512*512)
#define EPS 1e-8f

// Each block: 1024 consecutive pixels of one batch image. Each thread: 4 pixels
// via float4. Argmax over NC channels (strict >, ascending c => first-max
// tie-break, matches jnp.argmax).
//
// Round-2 changes vs the 494 us kernel:
//  (1) MLP: plane loads batched 7-at-a-time (21 = 3x7) in BOTH the argmax and
//      the target-scatter loops. The old code serialized ~42 global-load
//      round-trips per wave (VGPR_Count=32 => ~2 loads in flight); counters
//      showed 650 GB/s (8% peak) with VALUBusy 1.5% => pure vmcnt stall.
//      `#pragma unroll 1` on the group loop keeps VGPRs ~60 (8 waves/SIMD).
//  (2) LDS scatter contention: 4 replicas of the 21x21 tile indexed by
//      lane-group (t>>4)&3 -> intra-wave same-address ds_add serialization
//      cut ~4x. Replica stride 441 words (441 % 32 = 25) de-aliases banks.
__global__ __launch_bounds__(256) void cm_accum(const float* __restrict__ input,
                                                const float* __restrict__ target,
                                                float* __restrict__ cm /*[NB][NC][NC]*/) {
    __shared__ float scm[4][NC * NC];
    const int t = threadIdx.x;
    for (int i = t; i < 4 * NC * NC; i += 256) ((float*)scm)[i] = 0.0f;
    __syncthreads();

    const int b    = blockIdx.x >> 8;    // 256 tiles per batch
    const int tile = blockIdx.x & 255;
    const int q    = (tile << 8) + t;    // float4 index within a channel plane

    const float4* ip = (const float4*)(input  + (size_t)b * NC * HW);
    const float4* tp = (const float4*)(target + (size_t)b * NC * HW);
    const int plane4 = HW / 4;

    // ---- argmax over channels, 4 pixels at once, loads batched 7-deep ----
    float4 m;
    int jx = 0, jy = 0, jz = 0, jw = 0;
    {
        // group 0 (c = 0..6): issue 7 loads, then compare in channel order
        float4 v[7];
        #pragma unroll
        for (int u = 0; u < 7; ++u) v[u] = ip[u * plane4 + q];
        m = v[0];
        #pragma unroll
        for (int u = 1; u < 7; ++u) {
            if (v[u].x > m.x) { m.x = v[u].x; jx = u; }
            if (v[u].y > m.y) { m.y = v[u].y; jy = u; }
            if (v[u].z > m.z) { m.z = v[u].z; jz = u; }
            if (v[u].w > m.w) { m.w = v[u].w; jw = u; }
        }
    }
    #pragma unroll 1
    for (int g = 1; g < 3; ++g) {
        float4 v[7];
        const int c0 = g * 7;
        #pragma unroll
        for (int u = 0; u < 7; ++u) v[u] = ip[(c0 + u) * plane4 + q];
        #pragma unroll
        for (int u = 0; u < 7; ++u) {
            const int c = c0 + u;
            if (v[u].x > m.x) { m.x = v[u].x; jx = c; }
            if (v[u].y > m.y) { m.y = v[u].y; jy = c; }
            if (v[u].z > m.z) { m.z = v[u].z; jz = c; }
            if (v[u].w > m.w) { m.w = v[u].w; jw = c; }
        }
    }

    // ---- scatter target mass, loads batched 7-deep, lane-group replicas ----
    float* my = scm[(t >> 4) & 3];
    #pragma unroll 1
    for (int g = 0; g < 3; ++g) {
        float4 y[7];
        const int c0 = g * 7;
        #pragma unroll
        for (int u = 0; u < 7; ++u) y[u] = tp[(c0 + u) * plane4 + q];
        #pragma unroll
        for (int u = 0; u < 7; ++u) {
            const int row = (c0 + u) * NC;
            atomicAdd(&my[row + jx], y[u].x);
            atomicAdd(&my[row + jy], y[u].y);
            atomicAdd(&my[row + jz], y[u].z);
            atomicAdd(&my[row + jw], y[u].w);
        }
    }
    __syncthreads();

    // flush all 441 entries (strided loop: 441 > 256 threads)
    for (int i = t; i < NC * NC; i += 256) {
        const float s = scm[0][i] + scm[1][i] + scm[2][i] + scm[3][i];
        atomicAdd(&cm[b * NC * NC + i], s);
    }
}

// rowsum[b,i] = sum_j cm[b,i,j] (exact identity: one-hot sums to 1 per pixel),
// out[i,j] = mean_b cm[b,i,j] / (rowsum[b,i] + EPS)
__global__ __launch_bounds__(512) void cm_final(const float* __restrict__ cm,
                                                float* __restrict__ out) {
    __shared__ float rs[NB * NC];
    const int t = threadIdx.x;
    if (t < NB * NC) {
        const int b = t / NC, i = t % NC;
        float s = 0.0f;
        for (int j = 0; j < NC; ++j) s += cm[b * NC * NC + i * NC + j];
        rs[t] = s + EPS;
    }
    __syncthreads();
    if (t < NC * NC) {
        const int i = t / NC;
        float acc = 0.0f;
        for (int b = 0; b < NB; ++b) acc += cm[b * NC * NC + t] / rs[b * NC + i];
        out[t] = acc * (1.0f / NB);
    }
}

extern "C" void kernel_launch(void* const* d_in, const int* in_sizes, int n_in,
                              void* d_out, int out_size, void* d_ws, size_t ws_size,
                              hipStream_t stream) {
    const float* input  = (const float*)d_in[0];
    const float* target = (const float*)d_in[1];
    float* out = (float*)d_out;
    float* cm  = (float*)d_ws;   // NB*NC*NC floats

    hipMemsetAsync(cm, 0, NB * NC * NC * sizeof(float), stream);
    cm_accum<<<NB * 256, 256, 0, stream>>>(input, target, cm);
    cm_final<<<1, 512, 0, stream>>>(cm, out);
}